// Round 19
// baseline (233.526 us; speedup 1.0000x reference)
//
#include <hip/hip_runtime.h>
#include <cstddef>
#include <cstdint>

#define NH 16
#define HD 64
#define SLEN 1024
#define NB 64
#define DMODEL 1024

#define DOT4_ACC(acc, k, q) \
  acc = fmaf((k).x, (q).x, fmaf((k).y, (q).y, fmaf((k).z, (q).z, fmaf((k).w, (q).w, (acc)))))

#define FMA4_BCAST(accv, qv, w0_, w1_, w2_, w3_) do { \
  (accv).x = fmaf((qv).x, (w0_).x, fmaf((qv).y, (w1_).x, fmaf((qv).z, (w2_).x, fmaf((qv).w, (w3_).x, (accv).x)))); \
  (accv).y = fmaf((qv).x, (w0_).y, fmaf((qv).y, (w1_).y, fmaf((qv).z, (w2_).y, fmaf((qv).w, (w3_).y, (accv).y)))); \
  (accv).z = fmaf((qv).x, (w0_).z, fmaf((qv).y, (w1_).z, fmaf((qv).z, (w2_).z, fmaf((qv).w, (w3_).z, (accv).z)))); \
  (accv).w = fmaf((qv).x, (w0_).w, fmaf((qv).y, (w1_).w, fmaf((qv).z, (w2_).w, fmaf((qv).w, (w3_).w, (accv).w)))); \
} while (0)

#define VMCNT_WAIT(n) asm volatile("s_waitcnt vmcnt(" #n ")" ::: "memory")
#define BAR() asm volatile("s_barrier" ::: "memory")

__device__ __forceinline__ float wred_sum(float v) {
#pragma unroll
  for (int off = 32; off; off >>= 1) v += __shfl_xor(v, off, 64);
  return v;
}

__device__ __forceinline__ void gload16(const float* g, float* lds_base) {
  __builtin_amdgcn_global_load_lds(
      (const __attribute__((address_space(1))) void*)g,
      (__attribute__((address_space(3))) void*)lds_base, 16, 0, 0);
}

// K0 v3 (R18-identical): qp[b][j] = sum_c query[b][c] * Wq[j][c].
__global__ __launch_bounds__(256) void k0_qp(const float* __restrict__ query,
                                             const float* __restrict__ Wq,
                                             float* __restrict__ qp) {
  const int tid = threadIdx.x;
  const int w = tid >> 6, l = tid & 63;
  const int jq = blockIdx.x & 255;
  const int bq = blockIdx.x >> 8;      // 0..3
  const int j = jq * 4 + w;            // 0..1023
  const float4* wr = reinterpret_cast<const float4*>(Wq + (size_t)j * DMODEL) + l * 4;
  const float4 w0 = wr[0], w1 = wr[1], w2 = wr[2], w3 = wr[3];
  float acc[16];
#pragma unroll
  for (int bi = 0; bi < 16; ++bi) {
    const float4* qr = reinterpret_cast<const float4*>(
        query + (size_t)(bq * 16 + bi) * DMODEL) + l * 4;
    float4 q0 = qr[0], q1 = qr[1], q2 = qr[2], q3 = qr[3];
    float s = 0.f;
    DOT4_ACC(s, w0, q0); DOT4_ACC(s, w1, q1); DOT4_ACC(s, w2, q2); DOT4_ACC(s, w3, q3);
    acc[bi] = s;
  }
#pragma unroll
  for (int off = 32; off; off >>= 1) {
#pragma unroll
    for (int bi = 0; bi < 16; ++bi) acc[bi] += __shfl_xor(acc[bi], off, 64);
  }
  if (l == 0) {
#pragma unroll
    for (int bi = 0; bi < 16; ++bi)
      qp[(size_t)(bq * 16 + bi) * DMODEL + j] = acc[bi];
  }
}

// K1 (R18-identical): qt[b][h][m] = sum_d qp[b][h*64+d] * Wk[h*64+d][m].
__global__ __launch_bounds__(256) void k1_qt(const float* __restrict__ qp,
                                             const float* __restrict__ Wk,
                                             float* __restrict__ qt) {
  __shared__ __align__(16) float qpl[2][HD];
  const int h = blockIdx.x & 15;
  const int b0 = (blockIdx.x >> 4) * 2;
  const int tid = threadIdx.x;
  if (tid < 2 * HD) qpl[tid >> 6][tid & 63] =
      qp[(size_t)(b0 + (tid >> 6)) * DMODEL + h * HD + (tid & 63)];
  __syncthreads();
  const int m4 = tid * 4;
  float4 acc0 = make_float4(0.f, 0.f, 0.f, 0.f);
  float4 acc1 = make_float4(0.f, 0.f, 0.f, 0.f);
  const float* wbase = Wk + (size_t)(h * HD) * DMODEL + m4;
  for (int d = 0; d < HD; d += 4) {
    float4 wk0 = *reinterpret_cast<const float4*>(wbase + (size_t)(d + 0) * DMODEL);
    float4 wk1 = *reinterpret_cast<const float4*>(wbase + (size_t)(d + 1) * DMODEL);
    float4 wk2 = *reinterpret_cast<const float4*>(wbase + (size_t)(d + 2) * DMODEL);
    float4 wk3 = *reinterpret_cast<const float4*>(wbase + (size_t)(d + 3) * DMODEL);
    float4 qa = *reinterpret_cast<const float4*>(&qpl[0][d]);
    float4 qb = *reinterpret_cast<const float4*>(&qpl[1][d]);
    FMA4_BCAST(acc0, qa, wk0, wk1, wk2, wk3);
    FMA4_BCAST(acc1, qb, wk0, wk1, wk2, wk3);
  }
  *reinterpret_cast<float4*>(qt + ((size_t)(b0 + 0) * NH + h) * DMODEL + m4) = acc0;
  *reinterpret_cast<float4*>(qt + ((size_t)(b0 + 1) * NH + h) * DMODEL + m4) = acc1;
}

// K2 v15: FULL-ROW staging (k3's proven DRAM pattern) + lane-m compute via
// LDS transpose. Block = (b, st: 64-s tile, mh: m-half), 4 waves.
// Staging: each key half-row (512 fl = 2KB) loaded as 2 CONTIGUOUS gload16
// (page-efficient burst; every previous k2 used 64-256B slivers -> page
// thrash, ~2 TB/s vs k3's 5 TB/s). Wave w stages AND computes rows w*2,w*2+1
// of each 8-row group -> kb wave-private, NO in-loop barriers, vmcnt(4) only.
// qb (16x512, 32KB) staged once with f4^hh pre-swizzle at the GLOBAL source
// (LDS dest linear); reads apply same XOR -> <=2-way bank alias (free).
// Compute: lane = (mg=l&15 m-slot, hg=l>>4 head-quad); acc[2r][4h];
// 16-way shfl_xor fold over mg. LDS 64KB -> 2 blocks/CU.
__global__ __launch_bounds__(256, 2) void k2_scores(const float* __restrict__ keys,
                                                    const float* __restrict__ qt,
                                                    float* __restrict__ scp) {
  __shared__ __align__(16) float qb[NH][512];    // 32 KB
  __shared__ __align__(16) float kb[2][8][512];  // 32 KB
  const int b  = blockIdx.x & 63;
  const int st = (blockIdx.x >> 6) & 15;  // 0..15
  const int mh = blockIdx.x >> 10;        // 0..1
  const int tid = threadIdx.x, w = tid >> 6, l = tid & 63;
  const int mg = l & 15;                  // m-slot within 64-float pass
  const int hg = l >> 4;                  // head-quad 0..3
  const int s0 = st * 64;
  const size_t rowstride = (size_t)NB * DMODEL;
  const float* kbase = keys + ((size_t)s0 * NB + b) * DMODEL + mh * 512;
  const float* qbase = qt + (size_t)b * NH * DMODEL + mh * 512;

  // prologue: wave w stages q heads w*4..w*4+3 (f4-index pre-swizzled by ^hh)
#pragma unroll
  for (int i = 0; i < 4; ++i) {
    const int hh = w * 4 + i;
    const float* qrow = qbase + (size_t)hh * DMODEL;
#pragma unroll
    for (int c = 0; c < 2; ++c)
      gload16(qrow + (size_t)(c * 64 + (l ^ hh)) * 4, &qb[hh][c * 256]);
  }

#define K2_STAGE(buf_, g_) do {                                                \
    _Pragma("unroll")                                                          \
    for (int i_ = 0; i_ < 2; ++i_) {                                           \
      const int sr_ = (g_) * 8 + w * 2 + i_;                                   \
      const float* kr_ = kbase + (size_t)sr_ * rowstride;                      \
      _Pragma("unroll")                                                        \
      for (int c_ = 0; c_ < 2; ++c_)                                           \
        gload16(kr_ + (size_t)(c_ * 64 + l) * 4,                               \
                &kb[buf_][w * 2 + i_][c_ * 256]);                              \
    }                                                                          \
  } while (0)

  K2_STAGE(0, 0);
  VMCNT_WAIT(0);
  __syncthreads();   // qb visible to all waves (once; kb is wave-private)

  const float scale = 0.125f;  // 1/sqrt(64); linear -> distributes over m-halves
  float* plane = scp + (size_t)mh * NB * NH * SLEN;

  for (int g = 0; g < 8; ++g) {
    const int buf = g & 1;
    if (g + 1 < 8) {
      K2_STAGE(buf ^ 1, g + 1);  // issue next group's 4 loads FIRST
      VMCNT_WAIT(4);             // this wave's current-group rows landed
    } else {
      VMCNT_WAIT(0);
    }
    float acc[2][4];
#pragma unroll
    for (int r = 0; r < 2; ++r)
#pragma unroll
      for (int h = 0; h < 4; ++h) acc[r][h] = 0.f;
#pragma unroll
    for (int p = 0; p < 8; ++p) {
      float4 kv0 = *reinterpret_cast<const float4*>(
          &kb[buf][w * 2 + 0][(p * 16 + mg) * 4]);
      float4 kv1 = *reinterpret_cast<const float4*>(
          &kb[buf][w * 2 + 1][(p * 16 + mg) * 4]);
      float4 qv[4];
#pragma unroll
      for (int h = 0; h < 4; ++h) {
        const int hh = hg * 4 + h;
        qv[h] = *reinterpret_cast<const float4*>(
            &qb[hh][(p * 16 + (mg ^ hh)) * 4]);
      }
#pragma unroll
      for (int h = 0; h < 4; ++h) {
        DOT4_ACC(acc[0][h], kv0, qv[h]);
        DOT4_ACC(acc[1][h], kv1, qv[h]);
      }
    }
    // fold 16-way across mg (lane bits 0-3)
#pragma unroll
    for (int off = 1; off <= 8; off <<= 1)
#pragma unroll
      for (int r = 0; r < 2; ++r)
#pragma unroll
        for (int h = 0; h < 4; ++h)
          acc[r][h] += __shfl_xor(acc[r][h], off, 64);
    // lanes mg 0..7 write: r = mg>>2, h = mg&3
    if (mg < 8) {
      const int r = mg >> 2, h = mg & 3;
      plane[((size_t)b * NH + hg * 4 + h) * SLEN + s0 + g * 8 + w * 2 + r] =
          acc[r][h] * scale;
    }
  }
#undef K2_STAGE
}

// K_SM (R18-identical): sums the two partial planes, softmax, writes plane0.
__global__ __launch_bounds__(256) void k_sm(float* __restrict__ sc0,
                                            const float* __restrict__ sc1) {
  __shared__ float red[8];
  const int tid = threadIdx.x, w = tid >> 6, l = tid & 63;
  float* p0 = sc0 + (size_t)blockIdx.x * SLEN;
  const float* p1 = sc1 + (size_t)blockIdx.x * SLEN;
  float4 xa = reinterpret_cast<const float4*>(p0)[tid];
  float4 xb = reinterpret_cast<const float4*>(p1)[tid];
  float4 x = make_float4(xa.x + xb.x, xa.y + xb.y, xa.z + xb.z, xa.w + xb.w);
  float mx = fmaxf(fmaxf(x.x, x.y), fmaxf(x.z, x.w));
#pragma unroll
  for (int off = 32; off; off >>= 1) mx = fmaxf(mx, __shfl_xor(mx, off, 64));
  if (l == 0) red[w] = mx;
  __syncthreads();
  mx = fmaxf(fmaxf(red[0], red[1]), fmaxf(red[2], red[3]));
  float4 e;
  e.x = __expf(x.x - mx); e.y = __expf(x.y - mx);
  e.z = __expf(x.z - mx); e.w = __expf(x.w - mx);
  float sum = e.x + e.y + e.z + e.w;
  sum = wred_sum(sum);
  if (l == 0) red[4 + w] = sum;
  __syncthreads();
  sum = red[4] + red[5] + red[6] + red[7];
  const float inv = 1.f / sum;
  e.x *= inv; e.y *= inv; e.z *= inv; e.w *= inv;
  reinterpret_cast<float4*>(p0)[tid] = e;
}

// K3 (R18-identical): partial c[ch][b][h][m] = sum_{s in chunk} attn*values.
template <int NCH>
__global__ __launch_bounds__(256) void k3_cpart(const float* __restrict__ values,
                                                const float* __restrict__ attn,
                                                float* __restrict__ cp) {
  constexpr int SC = SLEN / NCH;
  __shared__ __align__(16) float vb[2][4][DMODEL];  // 32 KB
  __shared__ __align__(16) float al[NH][SC];
  const int b = blockIdx.x & 63;
  const int ch = blockIdx.x >> 6;
  const int s0 = ch * SC;
  const int tid = threadIdx.x, w = tid >> 6, l = tid & 63;
  for (int f = tid; f < NH * (SC / 4); f += 256) {
    int hh = f / (SC / 4), c4 = (f % (SC / 4)) * 4;
    *reinterpret_cast<float4*>(&al[hh][c4]) = *reinterpret_cast<const float4*>(
        attn + ((size_t)b * NH + hh) * SLEN + s0 + c4);
  }
  const int m4 = tid * 4;
  float4 acc[NH];
#pragma unroll
  for (int i = 0; i < NH; ++i) acc[i] = make_float4(0.f, 0.f, 0.f, 0.f);
  const size_t rowstride = (size_t)NB * DMODEL;
  const float* vbase = values + ((size_t)s0 * NB + b) * DMODEL;

#define K3_STAGE(buf_, g_) do {                                               \
    const float* rg_ = vbase + (size_t)((g_) * 4 + w) * rowstride;            \
    _Pragma("unroll")                                                         \
    for (int j_ = 0; j_ < 4; ++j_)                                            \
      gload16(rg_ + j_ * 256 + l * 4, &vb[buf_][w][j_ * 256]);                \
  } while (0)

  K3_STAGE(0, 0);
  __syncthreads();  // covers al fill + prologue stage
  for (int g = 0; g < SC / 4; ++g) {
    const int buf = g & 1;
    if (g + 1 < SC / 4) {
      K3_STAGE(buf ^ 1, g + 1);
      VMCNT_WAIT(4);
    } else {
      VMCNT_WAIT(0);
    }
    BAR();
    float4 v0 = *reinterpret_cast<const float4*>(&vb[buf][0][m4]);
    float4 v1 = *reinterpret_cast<const float4*>(&vb[buf][1][m4]);
    float4 v2 = *reinterpret_cast<const float4*>(&vb[buf][2][m4]);
    float4 v3 = *reinterpret_cast<const float4*>(&vb[buf][3][m4]);
#pragma unroll
    for (int hh = 0; hh < NH; ++hh) {
      float4 av = *reinterpret_cast<const float4*>(&al[hh][g * 4]);  // broadcast
      FMA4_BCAST(acc[hh], av, v0, v1, v2, v3);
    }
    BAR();
  }
#undef K3_STAGE
#pragma unroll
  for (int hh = 0; hh < NH; ++hh)
    *reinterpret_cast<float4*>(cp + (((size_t)ch * NB + b) * NH + hh) * DMODEL + m4) = acc[hh];
}

// K4 v2 (R18-identical): out[b][h*64+d] = sum_m Wk[h*64+d][m] * (sum_ch cp).
template <int NCH>
__global__ __launch_bounds__(256) void k4_out(const float* __restrict__ cp,
                                              const float* __restrict__ Wk,
                                              float* __restrict__ out) {
  __shared__ __align__(16) float cl[2 * DMODEL];
  const int h = blockIdx.x & 15;
  const int b0 = (blockIdx.x >> 4) * 2;
  const int tid = threadIdx.x, w = tid >> 6, l = tid & 63;
  for (int f = tid; f < 2 * DMODEL / 4; f += 256) {
    int bi = f >> 8, m4 = (f & 255) * 4;
    float4 s = make_float4(0.f, 0.f, 0.f, 0.f);
#pragma unroll
    for (int ch = 0; ch < NCH; ++ch) {
      float4 t = *reinterpret_cast<const float4*>(
          cp + (((size_t)ch * NB + b0 + bi) * NH + h) * DMODEL + m4);
      s.x += t.x; s.y += t.y; s.z += t.z; s.w += t.w;
    }
    *reinterpret_cast<float4*>(&cl[bi * DMODEL + m4]) = s;
  }
  __syncthreads();
  float4 c[2][4];
#pragma unroll
  for (int bi = 0; bi < 2; ++bi)
#pragma unroll
    for (int k = 0; k < 4; ++k)
      c[bi][k] = *reinterpret_cast<const float4*>(&cl[bi * DMODEL + l * 16 + k * 4]);
  for (int jj = 0; jj < 16; ++jj) {
    const int d = w * 16 + jj;
    const float4* wr = reinterpret_cast<const float4*>(Wk + (size_t)(h * HD + d) * DMODEL) + l * 4;
    const float4 w0 = wr[0], w1 = wr[1], w2 = wr[2], w3 = wr[3];
#pragma unroll
    for (int bi = 0; bi < 2; ++bi) {
      float s = 0.f;
      DOT4_ACC(s, w0, c[bi][0]); DOT4_ACC(s, w1, c[bi][1]);
      DOT4_ACC(s, w2, c[bi][2]); DOT4_ACC(s, w3, c[bi][3]);
      s = wred_sum(s);
      if (l == 0) out[(size_t)(b0 + bi) * (NH * HD) + h * HD + d] = s;
    }
  }
}

extern "C" void kernel_launch(void* const* d_in, const int* in_sizes, int n_in,
                              void* d_out, int out_size, void* d_ws, size_t ws_size,
                              hipStream_t stream) {
  const float* query  = (const float*)d_in[0];
  const float* keys   = (const float*)d_in[1];
  const float* values = (const float*)d_in[2];
  const float* Wq     = (const float*)d_in[3];
  const float* Wk     = (const float*)d_in[4];
  float* out = (float*)d_out;

  float* W   = (float*)d_ws;
  float* qp  = W;                                   // 64*1024
  float* qt  = qp + (size_t)NB * DMODEL;            // 64*16*1024
  float* sc0 = qt + (size_t)NB * NH * DMODEL;       // partial m-half 0 -> attn
  float* sc1 = sc0 + (size_t)NB * NH * SLEN;        // partial m-half 1
  float* cp  = sc1 + (size_t)NB * NH * SLEN;        // NCH*64*16*1024

  const size_t base_floats = (size_t)NB * DMODEL + (size_t)NB * NH * DMODEL
                           + 2 * (size_t)NB * NH * SLEN;

  k0_qp<<<1024, 256, 0, stream>>>(query, Wq, qp);
  k1_qt<<<512, 256, 0, stream>>>(qp, Wk, qt);
  k2_scores<<<2048, 256, 0, stream>>>(keys, qt, sc0);  // writes sc0 (mh=0) / sc1 (mh=1)
  k_sm<<<NB * NH, 256, 0, stream>>>(sc0, sc1);

  const size_t chunk_floats = (size_t)NB * NH * DMODEL;
  if (ws_size >= (base_floats + 16 * chunk_floats) * sizeof(float)) {
    k3_cpart<16><<<16 * NB, 256, 0, stream>>>(values, sc0, cp);
    k4_out<16><<<NH * (NB / 2), 256, 0, stream>>>(cp, Wk, out);
  } else if (ws_size >= (base_floats + 8 * chunk_floats) * sizeof(float)) {
    k3_cpart<8><<<8 * NB, 256, 0, stream>>>(values, sc0, cp);
    k4_out<8><<<NH * (NB / 2), 256, 0, stream>>>(cp, Wk, out);
  } else {
    k3_cpart<4><<<4 * NB, 256, 0, stream>>>(values, sc0, cp);
    k4_out<4><<<NH * (NB / 2), 256, 0, stream>>>(cp, Wk, out);
  }
}